// Round 3
// baseline (488.851 us; speedup 1.0000x reference)
//
#include <hip/hip_runtime.h>
#include <math.h>

// ---------------------------------------------------------------------------
// NatureCNN: conv×3 (implicit-im2col bf16 MFMA GEMMs, NHWC intermediates)
// | lin1+relu -> lin2 (bf16 MFMA) -> concat feat -> wih0 pre-act GEMMs (fp32 out)
// -> 2×(2-layer LSTM, fp32, k-split spill-free) -> head.
// ---------------------------------------------------------------------------

typedef __attribute__((ext_vector_type(4))) float f32x4;
typedef __attribute__((ext_vector_type(8))) short s16x8;
typedef __attribute__((ext_vector_type(8))) unsigned short u16x8;

__device__ __forceinline__ unsigned short f2bf(float f){
  union { float f; unsigned int u; } v; v.f = f;
  unsigned int r = (v.u + 0x7fffu + ((v.u >> 16) & 1u)) >> 16;
  return (unsigned short)r;
}
__device__ __forceinline__ float sigmoidf_(float x){ return 1.0f/(1.0f+__expf(-x)); }
__device__ __forceinline__ float tanhf_(float x){
  float e = __expf(-2.0f*fabsf(x));
  float t = (1.0f - e)/(1.0f + e);
  return copysignf(t, x);
}

// ---------------------------------------------------------------------------
// prep kernels (tiny, memory-bound)
// ---------------------------------------------------------------------------
__global__ void cast_pad_k(const float* __restrict__ src, unsigned short* __restrict__ dst,
                           int rows, int ks, int kd){
  int total = rows*kd;
  for (int e = blockIdx.x*blockDim.x + threadIdx.x; e < total; e += gridDim.x*blockDim.x){
    int r = e / kd, k = e - r*kd;
    dst[e] = (k < ks) ? f2bf(src[(size_t)r*ks + k]) : (unsigned short)0;
  }
}
// OIHW -> O,(tap,ci) : dst[oc*K + tap*cin + ic] = src[oc*K + ic*khkw + tap]
__global__ void reorder_w_k(const float* __restrict__ src, unsigned short* __restrict__ dst,
                            int ocn, int cin, int khkw){
  int K = cin*khkw, total = ocn*K;
  for (int e = blockIdx.x*blockDim.x + threadIdx.x; e < total; e += gridDim.x*blockDim.x){
    int oc = e / K, r = e - oc*K;
    int tap = r / cin, ic = r - tap*cin;
    dst[e] = f2bf(src[(size_t)oc*K + ic*khkw + tap]);
  }
}
// wih0 [400][1536]: permute k<1024 from (oc*16+p) order to NHWC-flat (p*64+oc)
__global__ void permute_wih_k(const float* __restrict__ src, unsigned short* __restrict__ dst){
  int total = 400*1536;
  for (int e = blockIdx.x*blockDim.x + threadIdx.x; e < total; e += gridDim.x*blockDim.x){
    int g = e / 1536, k = e - g*1536;
    int ksrc = (k < 1024) ? ((k & 63)*16 + (k >> 6)) : k;
    dst[e] = f2bf(src[(size_t)g*1536 + ksrc]);
  }
}
// six [400][100] -> [100][400] fp32 (LSTM register-cache layout)
__global__ void transpose6_k(const float* s0,const float* s1,const float* s2,
                             const float* s3,const float* s4,const float* s5,
                             float* __restrict__ dst){
  const float* srcs[6] = {s0,s1,s2,s3,s4,s5};
  const float* src = srcs[blockIdx.y];
  float* d = dst + (size_t)blockIdx.y*40000;
  int e = blockIdx.x*blockDim.x + threadIdx.x;
  if (e < 40000){ int k = e/400, g = e - k*400; d[e] = src[g*100 + k]; }
}

// ---------------------------------------------------------------------------
// bf16 MFMA GEMM: C = act(A * B^T + bias); B is [N][K] bf16 row-major.
// AMODE 0: A bf16 [M][lda].  1: conv1 gather from fp32 NCHW obs (k=ic*64+ky*8+kx).
//          2: NHWC bf16 conv gather (k=(ky*KW+kx)*CIN+ic).
// CMODE 0: bf16 row-major [M][ldc].  2: bf16 feat scatter (n*cstride + p*64 + col).
//          3: fp32 row-major (X0 path).
// All M are multiples of BM=128; K multiples of BK=64. NGUARD guards N (X0: N=400).
// ---------------------------------------------------------------------------
template<int BM,int BN,int WAVES_M,int WAVES_N,int AMODE,int CMODE,int RELU,int NGUARD,
         int CIN,int HI,int WI,int KH,int KW,int ST,int HO,int WO>
__global__ __launch_bounds__(256) void mgemm(
    const void* __restrict__ Av, const unsigned short* __restrict__ B,
    void* __restrict__ Cv, const float* __restrict__ bias,
    int M, int N, int K, int lda, int ldc, int cstride)
{
  constexpr int BK = 64;
  constexpr int WROWS = BM / WAVES_M;
  constexpr int WCOLS = BN / WAVES_N;
  constexpr int MF = WROWS / 16;
  constexpr int NF = WCOLS / 16;
  constexpr int HOWO = HO*WO;
  __shared__ unsigned short As[BM*BK];
  __shared__ unsigned short Bs[BN*BK];
  const int tid = threadIdx.x;
  const int bm = blockIdx.x * BM;
  const int bn = blockIdx.y * BN;
  const int lane = tid & 63, w = tid >> 6;
  const int wm = w / WAVES_N, wn = w % WAVES_N;
  const int m0 = wm * WROWS, n0 = wn * WCOLS;

  f32x4 acc[MF][NF] = {};

  const int ar = tid >> 1;           // A-stage row (BM=128 assumed)
  const int as0 = 4 * (tid & 1);     // A-stage slot base
  const int row_g = bm + ar;
  // im2col row decomposition (compile-time divisors)
  int a_n = 0, a_oy = 0, a_ox = 0;
  if (AMODE != 0){ a_n = row_g / HOWO; int p = row_g - a_n*HOWO; a_oy = p / WO; a_ox = p - a_oy*WO; }

  for (int kt = 0; kt < K; kt += BK){
    // ---- stage A ----
    #pragma unroll
    for (int si = 0; si < 4; ++si){
      int s = as0 + si;
      int k0 = kt + s*8;
      u16x8 val;
      if constexpr (AMODE == 0){
        val = *(const u16x8*)((const unsigned short*)Av + (size_t)row_g*lda + k0);
      } else if constexpr (AMODE == 1){
        int ic = k0 >> 6, r = k0 & 63, ky = r >> 3;   // kx0 == 0 (k0 % 8 == 0)
        const float* src = (const float*)Av +
            (((size_t)(a_n*CIN + ic)*HI + a_oy*ST + ky)*WI + a_ox*ST);
        f32x4 f0 = *(const f32x4*)src;
        f32x4 f1 = *(const f32x4*)(src + 4);
        val[0]=f2bf(f0[0]); val[1]=f2bf(f0[1]); val[2]=f2bf(f0[2]); val[3]=f2bf(f0[3]);
        val[4]=f2bf(f1[0]); val[5]=f2bf(f1[1]); val[6]=f2bf(f1[2]); val[7]=f2bf(f1[3]);
      } else {
        int tap = k0 / CIN, ic0 = k0 - tap*CIN;       // 8 | CIN, so 8-contig in ic
        int ky = tap / KW, kx = tap - ky*KW;
        const unsigned short* src = (const unsigned short*)Av +
            (((size_t)(a_n*HI + a_oy*ST + ky)*WI + a_ox*ST + kx)*CIN + ic0);
        val = *(const u16x8*)src;
      }
      int phys = s ^ ((ar >> 1) & 7);
      *(u16x8*)&As[ar*BK + phys*8] = val;
    }
    // ---- stage B ----
    if constexpr (BN == 64){
      int br = tid >> 2, bs0 = 2*(tid & 3);
      #pragma unroll
      for (int si = 0; si < 2; ++si){
        int s = bs0 + si, k0 = kt + s*8;
        int n_g = bn + br;
        u16x8 val = {};
        if (!NGUARD || n_g < N) val = *(const u16x8*)(B + (size_t)n_g*K + k0);
        int phys = s ^ ((br >> 1) & 7);
        *(u16x8*)&Bs[br*BK + phys*8] = val;
      }
    } else {  // BN == 32
      int br = tid >> 3, s = tid & 7, k0 = kt + s*8;
      int n_g = bn + br;
      u16x8 val = {};
      if (!NGUARD || n_g < N) val = *(const u16x8*)(B + (size_t)n_g*K + k0);
      int phys = s ^ ((br >> 1) & 7);
      *(u16x8*)&Bs[br*BK + phys*8] = val;
    }
    __syncthreads();
    // ---- compute: 2 MFMA k-steps per staged BK=64 ----
    #pragma unroll
    for (int ks = 0; ks < 2; ++ks){
      s16x8 a[MF], b[NF];
      #pragma unroll
      for (int i = 0; i < MF; ++i){
        int row = m0 + i*16 + (lane & 15);
        int phys = (ks*4 + (lane >> 4)) ^ ((row >> 1) & 7);
        a[i] = *(const s16x8*)&As[row*BK + phys*8];
      }
      #pragma unroll
      for (int j = 0; j < NF; ++j){
        int row = n0 + j*16 + (lane & 15);
        int phys = (ks*4 + (lane >> 4)) ^ ((row >> 1) & 7);
        b[j] = *(const s16x8*)&Bs[row*BK + phys*8];
      }
      #pragma unroll
      for (int i = 0; i < MF; ++i)
        #pragma unroll
        for (int j = 0; j < NF; ++j)
          acc[i][j] = __builtin_amdgcn_mfma_f32_16x16x32_bf16(a[i], b[j], acc[i][j], 0, 0, 0);
    }
    __syncthreads();
  }

  // ---- epilogue ----
  if constexpr (CMODE == 3){
    float* Cf = (float*)Cv;
    #pragma unroll
    for (int i = 0; i < MF; ++i)
      #pragma unroll
      for (int j = 0; j < NF; ++j){
        int col = bn + n0 + j*16 + (lane & 15);
        float bv = (bias && (!NGUARD || col < N)) ? bias[col] : 0.f;
        #pragma unroll
        for (int q = 0; q < 4; ++q){
          int row = bm + m0 + i*16 + (lane >> 4)*4 + q;
          float v = acc[i][j][q] + bv;
          if (RELU) v = fmaxf(v, 0.f);
          if (!NGUARD || col < N) Cf[(size_t)row*ldc + col] = v;
        }
      }
  } else {
    unsigned short* tile = As;   // reuse (BM*BN <= BM*BK)
    #pragma unroll
    for (int i = 0; i < MF; ++i)
      #pragma unroll
      for (int j = 0; j < NF; ++j){
        int col = n0 + j*16 + (lane & 15);
        float bv = bias ? bias[bn + col] : 0.f;
        #pragma unroll
        for (int q = 0; q < 4; ++q){
          int row = m0 + i*16 + (lane >> 4)*4 + q;
          float v = acc[i][j][q] + bv;
          if (RELU) v = fmaxf(v, 0.f);
          tile[row*BN + col] = f2bf(v);
        }
      }
    __syncthreads();
    unsigned short* Cu = (unsigned short*)Cv;
    constexpr int CHUNKS = (BM*BN)/(256*8);
    #pragma unroll
    for (int c = 0; c < CHUNKS; ++c){
      int flat = tid*8 + c*2048;
      int row = flat / BN, col = flat - (flat/BN)*BN;
      u16x8 v = *(const u16x8*)&tile[flat];
      int rg = bm + row;
      size_t addr;
      if constexpr (CMODE == 0) addr = (size_t)rg*ldc + bn + col;
      else { int n = rg >> 4, p = rg & 15; addr = (size_t)n*cstride + p*64 + col; }
      *(u16x8*)&Cu[addr] = v;
    }
  }
}

// ---------------------------------------------------------------------------
// LSTM: one block per segment; both stacks. 1024 threads; thread pair
// (2g, 2g+1) owns gate g with a 52/48 k-split of the dot product (52 weight
// floats per thread -> no spill at the 16-wave 128-VGPR cap). Halves combined
// with __shfl_xor(.,1). h/hbuf padded +4 and pad weights zeroed so both
// halves run an identical fully-unrolled 13x float4 loop.
// ---------------------------------------------------------------------------
__global__ __launch_bounds__(1024) void lstm_k(
    const float* __restrict__ X0s, const float* __restrict__ X0r,
    const float* __restrict__ wT,   // 6 x [100][400]: s_whh0,s_wih1,s_whh1,r_whh0,r_wih1,r_whh1
    const float* __restrict__ s_bih0, const float* __restrict__ s_bhh0,
    const float* __restrict__ s_bih1, const float* __restrict__ s_bhh1,
    const float* __restrict__ r_bih0, const float* __restrict__ r_bhh0,
    const float* __restrict__ r_bih1, const float* __restrict__ r_bhh1,
    float* __restrict__ outS, float* __restrict__ outR)
{
  __shared__ alignas(16) float h0[104];
  __shared__ alignas(16) float c0[104];
  __shared__ alignas(16) float h1[104];
  __shared__ alignas(16) float c1[104];
  __shared__ float gates[400];
  __shared__ alignas(16) float hbuf[3208];     // 32 x 100 (+pad)
  __shared__ alignas(16) float Xl1[12800];     // layer-1 x-part pre-acts, 32 x 400

  const int b = blockIdx.x, tid = threadIdx.x;
  const int g = tid >> 1, half = tid & 1;
  const bool act = (tid < 800);                // g < 400
  const int kbase = half * 13;                 // float4 index base into h/x rows

  if (tid < 104){ h0[tid]=0.f; c0[tid]=0.f; h1[tid]=0.f; c1[tid]=0.f; }
  if (tid >= 1016) hbuf[3200 + (tid-1016)] = 0.f;   // pad tail
  __syncthreads();

  #pragma unroll 1
  for (int s = 0; s < 2; ++s){
    const float* Xp   = (s ? X0r : X0s) + (size_t)b*32*400;
    const float* w0T  = wT + (size_t)(s ? 3 : 0)*40000;
    const float* w1xT = wT + (size_t)(s ? 4 : 1)*40000;
    const float* w1hT = wT + (size_t)(s ? 5 : 2)*40000;
    const float* bi0 = s ? r_bih0 : s_bih0;
    const float* bh0 = s ? r_bhh0 : s_bhh0;
    const float* bi1 = s ? r_bih1 : s_bih1;
    const float* bh1 = s ? r_bhh1 : s_bhh1;

    // ------------- layer 0 (recurrent) -------------
    {
      float wr[52];
      float bsum = 0.f, xcur = 0.f;
      if (act){
        #pragma unroll
        for (int j = 0; j < 52; ++j){
          int k = half*52 + j;
          wr[j] = (k < 100) ? w0T[k*400 + g] : 0.f;
        }
        if (!half){ bsum = bi0[g] + bh0[g]; xcur = Xp[g]; }
      }
      #pragma unroll 1
      for (int t = 0; t < 32; ++t){
        float xnext = 0.f;
        if (act && !half && t < 31) xnext = Xp[(t+1)*400 + g];
        float full = 0.f;
        if (act){
          const float4* h4 = (const float4*)h0;
          float a0=0.f,a1=0.f,a2=0.f,a3=0.f;
          #pragma unroll
          for (int kq = 0; kq < 13; ++kq){
            float4 hv = h4[kbase + kq];
            a0 += hv.x*wr[4*kq+0];
            a1 += hv.y*wr[4*kq+1];
            a2 += hv.z*wr[4*kq+2];
            a3 += hv.w*wr[4*kq+3];
          }
          float part = (a0+a1)+(a2+a3);
          full = part + __shfl_xor(part, 1);
          if (!half) gates[g] = xcur + bsum + full;
        }
        __syncthreads();
        if (tid < 100){
          float i_s = sigmoidf_(gates[tid]);
          float f_s = sigmoidf_(gates[100+tid]);
          float g_t = tanhf_(gates[200+tid]);
          float o_s = sigmoidf_(gates[300+tid]);
          float cn = f_s*c0[tid] + i_s*g_t;
          c0[tid] = cn;
          float hn = o_s*tanhf_(cn);
          h0[tid] = hn;
          hbuf[t*100+tid] = hn;
        }
        __syncthreads();
        xcur = xnext;
      }
    }
    // ------------- layer 1a: x-part pre-acts (no recurrence) -------------
    {
      float wx[52];
      float bsum = 0.f;
      if (act){
        #pragma unroll
        for (int j = 0; j < 52; ++j){
          int k = half*52 + j;
          wx[j] = (k < 100) ? w1xT[k*400 + g] : 0.f;
        }
        if (!half) bsum = bi1[g] + bh1[g];
        #pragma unroll 1
        for (int t = 0; t < 32; ++t){
          const float4* x4 = (const float4*)&hbuf[t*100];
          float a0=0.f,a1=0.f,a2=0.f,a3=0.f;
          #pragma unroll
          for (int kq = 0; kq < 13; ++kq){
            float4 xv = x4[kbase + kq];
            a0 += xv.x*wx[4*kq+0];
            a1 += xv.y*wx[4*kq+1];
            a2 += xv.z*wx[4*kq+2];
            a3 += xv.w*wx[4*kq+3];
          }
          float part = (a0+a1)+(a2+a3);
          float full = part + __shfl_xor(part, 1);
          if (!half) Xl1[t*400+g] = bsum + full;
        }
      }
      __syncthreads();
    }
    // ------------- layer 1b: recurrent -------------
    {
      float wh[52];
      if (act){
        #pragma unroll
        for (int j = 0; j < 52; ++j){
          int k = half*52 + j;
          wh[j] = (k < 100) ? w1hT[k*400 + g] : 0.f;
        }
      }
      #pragma unroll 1
      for (int t = 0; t < 32; ++t){
        if (act){
          const float4* h4 = (const float4*)h1;
          float a0=0.f,a1=0.f,a2=0.f,a3=0.f;
          #pragma unroll
          for (int kq = 0; kq < 13; ++kq){
            float4 hv = h4[kbase + kq];
            a0 += hv.x*wh[4*kq+0];
            a1 += hv.y*wh[4*kq+1];
            a2 += hv.z*wh[4*kq+2];
            a3 += hv.w*wh[4*kq+3];
          }
          float part = (a0+a1)+(a2+a3);
          float full = part + __shfl_xor(part, 1);
          if (!half) gates[g] = Xl1[t*400+g] + full;
        }
        __syncthreads();
        if (tid < 100){
          float i_s = sigmoidf_(gates[tid]);
          float f_s = sigmoidf_(gates[100+tid]);
          float g_t = tanhf_(gates[200+tid]);
          float o_s = sigmoidf_(gates[300+tid]);
          float cn = f_s*c1[tid] + i_s*g_t;
          c1[tid] = cn;
          float hn = o_s*tanhf_(cn);
          h1[tid] = hn;
          if (t == 31){
            float* dst = s ? outR : outS;
            dst[b*100+tid] = hn;
          }
        }
        __syncthreads();
      }
    }
  }
}

// Final head: out = relu([outR|outS] @ fc1^T + b1) @ fc2^T + b2
__global__ __launch_bounds__(256) void head_k(
    const float* __restrict__ outR, const float* __restrict__ outS,
    const float* __restrict__ f1w, const float* __restrict__ f1b,
    const float* __restrict__ f2w, const float* __restrict__ f2b,
    float* __restrict__ out)
{
  __shared__ float xin[200];
  __shared__ float mid[512];
  int b = blockIdx.x, tid = threadIdx.x;
  if (tid < 100) xin[tid] = outR[b*100+tid];
  else if (tid < 200) xin[tid] = outS[b*100+tid-100];
  __syncthreads();
  for (int j = tid; j < 512; j += 256){
    float acc = f1b[j];
    #pragma unroll 4
    for (int k=0;k<200;k++) acc += xin[k]*f1w[j*200+k];
    mid[j] = fmaxf(acc, 0.f);
  }
  __syncthreads();
  if (tid < 130){
    float acc = f2b[tid];
    #pragma unroll 4
    for (int k=0;k<512;k++) acc += mid[k]*f2w[tid*512+k];
    out[b*130+tid] = acc;
  }
}

extern "C" void kernel_launch(void* const* d_in, const int* in_sizes, int n_in,
                              void* d_out, int out_size, void* d_ws, size_t ws_size,
                              hipStream_t stream)
{
  const float* obs  = (const float*)d_in[0];
  const float* data = (const float*)d_in[1];
  const float* c1w = (const float*)d_in[2];  const float* c1b = (const float*)d_in[3];
  const float* c2w = (const float*)d_in[4];  const float* c2b = (const float*)d_in[5];
  const float* c3w = (const float*)d_in[6];  const float* c3b = (const float*)d_in[7];
  const float* l1w = (const float*)d_in[8];  const float* l1b = (const float*)d_in[9];
  const float* l2w = (const float*)d_in[10]; const float* l2b = (const float*)d_in[11];
  const float* s_wih0=(const float*)d_in[12]; const float* s_whh0=(const float*)d_in[13];
  const float* s_bih0=(const float*)d_in[14]; const float* s_bhh0=(const float*)d_in[15];
  const float* s_wih1=(const float*)d_in[16]; const float* s_whh1=(const float*)d_in[17];
  const float* s_bih1=(const float*)d_in[18]; const float* s_bhh1=(const float*)d_in[19];
  const float* r_wih0=(const float*)d_in[20]; const float* r_whh0=(const float*)d_in[21];
  const float* r_bih0=(const float*)d_in[22]; const float* r_bhh0=(const float*)d_in[23];
  const float* r_wih1=(const float*)d_in[24]; const float* r_whh1=(const float*)d_in[25];
  const float* r_bih1=(const float*)d_in[26]; const float* r_bhh1=(const float*)d_in[27];
  const float* f1w=(const float*)d_in[28]; const float* f1b=(const float*)d_in[29];
  const float* f2w=(const float*)d_in[30]; const float* f2b=(const float*)d_in[31];
  float* out = (float*)d_out;
  (void)in_sizes; (void)n_in; (void)out_size;

  // ---- workspace layout (bytes, 256-aligned); total ≈ 67 MB ----
  char* p = (char*)d_ws;
  auto alloc = [&](size_t bytes){ void* r = (void*)p; p += (bytes + 255) & ~(size_t)255; return r; };
  unsigned short* data_bf = (unsigned short*)alloc((size_t)2048*1536*2);
  unsigned short* c1w_bf  = (unsigned short*)alloc((size_t)32*192*2);
  unsigned short* c2w_bf  = (unsigned short*)alloc((size_t)64*512*2);
  unsigned short* c3w_bf  = (unsigned short*)alloc((size_t)64*576*2);
  unsigned short* l1w_bf  = (unsigned short*)alloc((size_t)1024*1536*2);
  unsigned short* l2w_bf  = (unsigned short*)alloc((size_t)512*1024*2);
  unsigned short* wihS_bf = (unsigned short*)alloc((size_t)400*1536*2);
  unsigned short* wihR_bf = (unsigned short*)alloc((size_t)400*1536*2);
  unsigned short* conv1o  = (unsigned short*)alloc((size_t)2048*225*32*2);  // NHWC
  unsigned short* conv2o  = (unsigned short*)alloc((size_t)2048*36*64*2);   // NHWC
  unsigned short* feat    = (unsigned short*)alloc((size_t)2048*1536*2);
  unsigned short* lin1o   = (unsigned short*)alloc((size_t)2048*1024*2);
  float* X0s  = (float*)alloc((size_t)1024*400*4);
  float* X0r  = (float*)alloc((size_t)1024*400*4);
  float* wT   = (float*)alloc((size_t)6*40000*4);
  float* outS = (float*)alloc(3200*4);
  float* outR = (float*)alloc(3200*4);
  (void)ws_size;

  // ---- prep: casts / reorders (independent of GEMMs) ----
  cast_pad_k<<<1024,256,0,stream>>>(data, data_bf, 2048, 1500, 1536);
  cast_pad_k<<<512,256,0,stream>>>(l1w, l1w_bf, 1024, 1500, 1536);
  cast_pad_k<<<512,256,0,stream>>>(l2w, l2w_bf, 512, 1024, 1024);
  cast_pad_k<<<32,256,0,stream>>>(c1w, c1w_bf, 32, 192, 192);
  reorder_w_k<<<128,256,0,stream>>>(c2w, c2w_bf, 64, 32, 16);
  reorder_w_k<<<144,256,0,stream>>>(c3w, c3w_bf, 64, 64, 9);
  permute_wih_k<<<512,256,0,stream>>>(s_wih0, wihS_bf);
  permute_wih_k<<<512,256,0,stream>>>(r_wih0, wihR_bf);
  transpose6_k<<<dim3(157,6),256,0,stream>>>(s_whh0, s_wih1, s_whh1,
                                             r_whh0, r_wih1, r_whh1, wT);

  // ---- GEMM chain (bf16 MFMA, fp32 accumulate) ----
  // conv1: M=460800 N=32 K=192, obs fp32 NCHW gather -> NHWC bf16
  mgemm<128,32,4,1, 1,0,1,0, 3,64,64,8,8,4,15,15><<<dim3(3600,1),256,0,stream>>>(
      obs, c1w_bf, conv1o, c1b, 460800, 32, 192, 0, 32, 0);
  // conv2: M=73728 N=64 K=512, NHWC gather -> NHWC bf16
  mgemm<128,64,2,2, 2,0,1,0, 32,15,15,4,4,2,6,6><<<dim3(576,1),256,0,stream>>>(
      conv1o, c2w_bf, conv2o, c2b, 73728, 64, 512, 0, 64, 0);
  // lin1: M=2048 N=1024 K=1536(padded) -> bf16
  mgemm<128,64,2,2, 0,0,1,0, 1,1,1,1,1,1,1,1><<<dim3(16,16),256,0,stream>>>(
      data_bf, l1w_bf, lin1o, l1b, 2048, 1024, 1536, 1536, 1024, 0);
  // conv3: M=32768 N=64 K=576 -> feat cols [0,1024) in NHWC-flat order
  mgemm<128,64,2,2, 2,2,1,0, 64,6,6,3,3,1,4,4><<<dim3(256,1),256,0,stream>>>(
      conv2o, c3w_bf, feat, c3b, 32768, 64, 576, 0, 0, 1536);
  // lin2: M=2048 N=512 K=1024 -> feat cols [1024,1536)
  mgemm<128,64,2,2, 0,0,0,0, 1,1,1,1,1,1,1,1><<<dim3(16,8),256,0,stream>>>(
      lin1o, l2w_bf, feat + 1024, l2b, 2048, 512, 1024, 1024, 1536, 0);
  // LSTM layer-0 input pre-acts (fp32 out, no bias)
  mgemm<128,64,2,2, 0,3,0,1, 1,1,1,1,1,1,1,1><<<dim3(8,7),256,0,stream>>>(
      feat, wihS_bf, X0s, (const float*)nullptr, 1024, 400, 1536, 1536, 400, 0);
  mgemm<128,64,2,2, 0,3,0,1, 1,1,1,1,1,1,1,1><<<dim3(8,7),256,0,stream>>>(
      feat + (size_t)1024*1536, wihR_bf, X0r, (const float*)nullptr, 1024, 400, 1536, 1536, 400, 0);

  // ---- sequential LSTM (fp32) + head ----
  lstm_k<<<32,1024,0,stream>>>(X0s, X0r, wT,
                               s_bih0,s_bhh0,s_bih1,s_bhh1,
                               r_bih0,r_bhh0,r_bih1,r_bhh1, outS, outR);
  head_k<<<32,256,0,stream>>>(outR, outS, f1w, f1b, f2w, f2b, out);
}

// Round 4
// 429.783 us; speedup vs baseline: 1.1374x; 1.1374x over previous
//
#include <hip/hip_runtime.h>
#include <math.h>

// ---------------------------------------------------------------------------
// NatureCNN: conv×3 (implicit-im2col bf16 MFMA GEMMs, NHWC intermediates)
// | lin1+relu -> lin2 (bf16 MFMA) -> concat feat -> wih0 pre-act GEMMs (fp32 out)
// -> 2×(2-layer LSTM, fp32, k-split spill-free) -> head.
// ---------------------------------------------------------------------------

typedef __attribute__((ext_vector_type(4))) float f32x4;
typedef __attribute__((ext_vector_type(8))) short s16x8;
typedef __attribute__((ext_vector_type(8))) unsigned short u16x8;

__device__ __forceinline__ unsigned short f2bf(float f){
  union { float f; unsigned int u; } v; v.f = f;
  unsigned int r = (v.u + 0x7fffu + ((v.u >> 16) & 1u)) >> 16;
  return (unsigned short)r;
}
__device__ __forceinline__ float sigmoidf_(float x){ return 1.0f/(1.0f+__expf(-x)); }
__device__ __forceinline__ float tanhf_(float x){
  float e = __expf(-2.0f*fabsf(x));
  float t = (1.0f - e)/(1.0f + e);
  return copysignf(t, x);
}

// ---------------------------------------------------------------------------
// prep kernels (tiny, memory-bound)
// ---------------------------------------------------------------------------
__global__ void cast_pad_k(const float* __restrict__ src, unsigned short* __restrict__ dst,
                           int rows, int ks, int kd){
  int total = rows*kd;
  for (int e = blockIdx.x*blockDim.x + threadIdx.x; e < total; e += gridDim.x*blockDim.x){
    int r = e / kd, k = e - r*kd;
    dst[e] = (k < ks) ? f2bf(src[(size_t)r*ks + k]) : (unsigned short)0;
  }
}
// OIHW -> O,(tap,ci) : dst[oc*K + tap*cin + ic] = src[oc*K + ic*khkw + tap]
__global__ void reorder_w_k(const float* __restrict__ src, unsigned short* __restrict__ dst,
                            int ocn, int cin, int khkw){
  int K = cin*khkw, total = ocn*K;
  for (int e = blockIdx.x*blockDim.x + threadIdx.x; e < total; e += gridDim.x*blockDim.x){
    int oc = e / K, r = e - oc*K;
    int tap = r / cin, ic = r - tap*cin;
    dst[e] = f2bf(src[(size_t)oc*K + ic*khkw + tap]);
  }
}
// wih0 [400][1536]: permute k<1024 from (oc*16+p) order to NHWC-flat (p*64+oc)
__global__ void permute_wih_k(const float* __restrict__ src, unsigned short* __restrict__ dst){
  int total = 400*1536;
  for (int e = blockIdx.x*blockDim.x + threadIdx.x; e < total; e += gridDim.x*blockDim.x){
    int g = e / 1536, k = e - g*1536;
    int ksrc = (k < 1024) ? ((k & 63)*16 + (k >> 6)) : k;
    dst[e] = f2bf(src[(size_t)g*1536 + ksrc]);
  }
}
// six [400][100] -> [100][400] fp32 (LSTM register-cache layout)
__global__ void transpose6_k(const float* s0,const float* s1,const float* s2,
                             const float* s3,const float* s4,const float* s5,
                             float* __restrict__ dst){
  const float* srcs[6] = {s0,s1,s2,s3,s4,s5};
  const float* src = srcs[blockIdx.y];
  float* d = dst + (size_t)blockIdx.y*40000;
  int e = blockIdx.x*blockDim.x + threadIdx.x;
  if (e < 40000){ int k = e/400, g = e - k*400; d[e] = src[g*100 + k]; }
}

// ---------------------------------------------------------------------------
// bf16 MFMA GEMM: C = act(A * B^T + bias); B is [N][K] bf16 row-major.
// AMODE 0: A bf16 [M][lda].  1: conv1 gather from fp32 NCHW obs (k=ic*64+ky*8+kx).
//          2: NHWC bf16 conv gather (k=(ky*KW+kx)*CIN+ic).
// CMODE 0: bf16 row-major [M][ldc].  2: bf16 feat scatter (n*cstride + p*64 + col).
//          3: fp32 row-major (X0 path).
// All M are multiples of BM=128; K multiples of BK=64. NGUARD guards N (X0: N=400).
// ---------------------------------------------------------------------------
template<int BM,int BN,int WAVES_M,int WAVES_N,int AMODE,int CMODE,int RELU,int NGUARD,
         int CIN,int HI,int WI,int KH,int KW,int ST,int HO,int WO>
__global__ __launch_bounds__(256) void mgemm(
    const void* __restrict__ Av, const unsigned short* __restrict__ B,
    void* __restrict__ Cv, const float* __restrict__ bias,
    int M, int N, int K, int lda, int ldc, int cstride)
{
  constexpr int BK = 64;
  constexpr int WROWS = BM / WAVES_M;
  constexpr int WCOLS = BN / WAVES_N;
  constexpr int MF = WROWS / 16;
  constexpr int NF = WCOLS / 16;
  constexpr int HOWO = HO*WO;
  __shared__ unsigned short As[BM*BK];
  __shared__ unsigned short Bs[BN*BK];
  const int tid = threadIdx.x;
  const int bm = blockIdx.x * BM;
  const int bn = blockIdx.y * BN;
  const int lane = tid & 63, w = tid >> 6;
  const int wm = w / WAVES_N, wn = w % WAVES_N;
  const int m0 = wm * WROWS, n0 = wn * WCOLS;

  f32x4 acc[MF][NF] = {};

  const int ar = tid >> 1;           // A-stage row (BM=128 assumed)
  const int as0 = 4 * (tid & 1);     // A-stage slot base
  const int row_g = bm + ar;
  // im2col row decomposition (compile-time divisors)
  int a_n = 0, a_oy = 0, a_ox = 0;
  if (AMODE != 0){ a_n = row_g / HOWO; int p = row_g - a_n*HOWO; a_oy = p / WO; a_ox = p - a_oy*WO; }

  for (int kt = 0; kt < K; kt += BK){
    // ---- stage A ----
    #pragma unroll
    for (int si = 0; si < 4; ++si){
      int s = as0 + si;
      int k0 = kt + s*8;
      u16x8 val;
      if constexpr (AMODE == 0){
        val = *(const u16x8*)((const unsigned short*)Av + (size_t)row_g*lda + k0);
      } else if constexpr (AMODE == 1){
        int ic = k0 >> 6, r = k0 & 63, ky = r >> 3;   // kx0 == 0 (k0 % 8 == 0)
        const float* src = (const float*)Av +
            (((size_t)(a_n*CIN + ic)*HI + a_oy*ST + ky)*WI + a_ox*ST);
        f32x4 f0 = *(const f32x4*)src;
        f32x4 f1 = *(const f32x4*)(src + 4);
        val[0]=f2bf(f0[0]); val[1]=f2bf(f0[1]); val[2]=f2bf(f0[2]); val[3]=f2bf(f0[3]);
        val[4]=f2bf(f1[0]); val[5]=f2bf(f1[1]); val[6]=f2bf(f1[2]); val[7]=f2bf(f1[3]);
      } else {
        int tap = k0 / CIN, ic0 = k0 - tap*CIN;       // 8 | CIN, so 8-contig in ic
        int ky = tap / KW, kx = tap - ky*KW;
        const unsigned short* src = (const unsigned short*)Av +
            (((size_t)(a_n*HI + a_oy*ST + ky)*WI + a_ox*ST + kx)*CIN + ic0);
        val = *(const u16x8*)src;
      }
      int phys = s ^ ((ar >> 1) & 7);
      *(u16x8*)&As[ar*BK + phys*8] = val;
    }
    // ---- stage B ----
    if constexpr (BN == 64){
      int br = tid >> 2, bs0 = 2*(tid & 3);
      #pragma unroll
      for (int si = 0; si < 2; ++si){
        int s = bs0 + si, k0 = kt + s*8;
        int n_g = bn + br;
        u16x8 val = {};
        if (!NGUARD || n_g < N) val = *(const u16x8*)(B + (size_t)n_g*K + k0);
        int phys = s ^ ((br >> 1) & 7);
        *(u16x8*)&Bs[br*BK + phys*8] = val;
      }
    } else {  // BN == 32
      int br = tid >> 3, s = tid & 7, k0 = kt + s*8;
      int n_g = bn + br;
      u16x8 val = {};
      if (!NGUARD || n_g < N) val = *(const u16x8*)(B + (size_t)n_g*K + k0);
      int phys = s ^ ((br >> 1) & 7);
      *(u16x8*)&Bs[br*BK + phys*8] = val;
    }
    __syncthreads();
    // ---- compute: 2 MFMA k-steps per staged BK=64 ----
    #pragma unroll
    for (int ks = 0; ks < 2; ++ks){
      s16x8 a[MF], b[NF];
      #pragma unroll
      for (int i = 0; i < MF; ++i){
        int row = m0 + i*16 + (lane & 15);
        int phys = (ks*4 + (lane >> 4)) ^ ((row >> 1) & 7);
        a[i] = *(const s16x8*)&As[row*BK + phys*8];
      }
      #pragma unroll
      for (int j = 0; j < NF; ++j){
        int row = n0 + j*16 + (lane & 15);
        int phys = (ks*4 + (lane >> 4)) ^ ((row >> 1) & 7);
        b[j] = *(const s16x8*)&Bs[row*BK + phys*8];
      }
      #pragma unroll
      for (int i = 0; i < MF; ++i)
        #pragma unroll
        for (int j = 0; j < NF; ++j)
          acc[i][j] = __builtin_amdgcn_mfma_f32_16x16x32_bf16(a[i], b[j], acc[i][j], 0, 0, 0);
    }
    __syncthreads();
  }

  // ---- epilogue ----
  if constexpr (CMODE == 3){
    float* Cf = (float*)Cv;
    #pragma unroll
    for (int i = 0; i < MF; ++i)
      #pragma unroll
      for (int j = 0; j < NF; ++j){
        int col = bn + n0 + j*16 + (lane & 15);
        float bv = (bias && (!NGUARD || col < N)) ? bias[col] : 0.f;
        #pragma unroll
        for (int q = 0; q < 4; ++q){
          int row = bm + m0 + i*16 + (lane >> 4)*4 + q;
          float v = acc[i][j][q] + bv;
          if (RELU) v = fmaxf(v, 0.f);
          if (!NGUARD || col < N) Cf[(size_t)row*ldc + col] = v;
        }
      }
  } else {
    unsigned short* tile = As;   // reuse (BM*BN <= BM*BK)
    #pragma unroll
    for (int i = 0; i < MF; ++i)
      #pragma unroll
      for (int j = 0; j < NF; ++j){
        int col = n0 + j*16 + (lane & 15);
        float bv = bias ? bias[bn + col] : 0.f;
        #pragma unroll
        for (int q = 0; q < 4; ++q){
          int row = m0 + i*16 + (lane >> 4)*4 + q;
          float v = acc[i][j][q] + bv;
          if (RELU) v = fmaxf(v, 0.f);
          tile[row*BN + col] = f2bf(v);
        }
      }
    __syncthreads();
    unsigned short* Cu = (unsigned short*)Cv;
    constexpr int CHUNKS = (BM*BN)/(256*8);
    #pragma unroll
    for (int c = 0; c < CHUNKS; ++c){
      int flat = tid*8 + c*2048;
      int row = flat / BN, col = flat - (flat/BN)*BN;
      u16x8 v = *(const u16x8*)&tile[flat];
      int rg = bm + row;
      size_t addr;
      if constexpr (CMODE == 0) addr = (size_t)rg*ldc + bn + col;
      else { int n = rg >> 4, p = rg & 15; addr = (size_t)n*cstride + p*64 + col; }
      *(u16x8*)&Cu[addr] = v;
    }
  }
}

// ---------------------------------------------------------------------------
// LSTM: one block per segment; both stacks. 832 threads (13 waves, 1 block/CU,
// min 4 waves/EU -> 128-VGPR budget). Thread pair (2g, 2g+1) owns gate g with
// a 52/48 k-split (52 weight floats/thread + ~30 state < 128 VGPR: spill-free).
// Gate threads also apply sigmoid/tanh (400-way parallel); the tid<100
// combiner only does cn/hn. h/hbuf padded +4, pad weights zeroed so both
// halves run an identical fully-unrolled 13x float4 loop.
// ---------------------------------------------------------------------------
__global__ __launch_bounds__(832,4) void lstm_k(
    const float* __restrict__ X0s, const float* __restrict__ X0r,
    const float* __restrict__ wT,   // 6 x [100][400]: s_whh0,s_wih1,s_whh1,r_whh0,r_wih1,r_whh1
    const float* __restrict__ s_bih0, const float* __restrict__ s_bhh0,
    const float* __restrict__ s_bih1, const float* __restrict__ s_bhh1,
    const float* __restrict__ r_bih0, const float* __restrict__ r_bhh0,
    const float* __restrict__ r_bih1, const float* __restrict__ r_bhh1,
    float* __restrict__ outS, float* __restrict__ outR)
{
  __shared__ alignas(16) float h0[104];
  __shared__ alignas(16) float c0[104];
  __shared__ alignas(16) float h1[104];
  __shared__ alignas(16) float c1[104];
  __shared__ float gates[400];                 // ACTIVATED gate values
  __shared__ alignas(16) float hbuf[3208];     // 32 x 100 (+pad)
  __shared__ alignas(16) float Xl1[12800];     // layer-1 x-part pre-acts, 32 x 400

  const int b = blockIdx.x, tid = threadIdx.x;
  const int g = tid >> 1, half = tid & 1;
  const bool act = (tid < 800);                // g < 400
  const int kbase = half * 13;                 // float4 index base into h/x rows
  const bool isG = (g >= 200) & (g < 300);     // tanh gate vs sigmoid gates

  if (tid < 104){ h0[tid]=0.f; c0[tid]=0.f; h1[tid]=0.f; c1[tid]=0.f; }
  if (tid >= 824) hbuf[3200 + (tid-824)] = 0.f;   // pad tail (8 entries)
  __syncthreads();

  #pragma unroll 1
  for (int s = 0; s < 2; ++s){
    const float* Xp   = (s ? X0r : X0s) + (size_t)b*32*400;
    const float* w0T  = wT + (size_t)(s ? 3 : 0)*40000;
    const float* w1xT = wT + (size_t)(s ? 4 : 1)*40000;
    const float* w1hT = wT + (size_t)(s ? 5 : 2)*40000;
    const float* bi0 = s ? r_bih0 : s_bih0;
    const float* bh0 = s ? r_bhh0 : s_bhh0;
    const float* bi1 = s ? r_bih1 : s_bih1;
    const float* bh1 = s ? r_bhh1 : s_bhh1;

    // ------------- layer 0 (recurrent) -------------
    {
      float wr[52];
      float bsum = 0.f, xcur = 0.f;
      if (act){
        #pragma unroll
        for (int j = 0; j < 52; ++j){
          int k = half*52 + j;
          wr[j] = (k < 100) ? w0T[k*400 + g] : 0.f;
        }
        if (!half){ bsum = bi0[g] + bh0[g]; xcur = Xp[g]; }
      }
      #pragma unroll 1
      for (int t = 0; t < 32; ++t){
        float xnext = 0.f;
        if (act && !half && t < 31) xnext = Xp[(t+1)*400 + g];
        if (act){
          const float4* h4 = (const float4*)h0;
          float a0=0.f,a1=0.f,a2=0.f,a3=0.f;
          #pragma unroll
          for (int kq = 0; kq < 13; ++kq){
            float4 hv = h4[kbase + kq];
            a0 += hv.x*wr[4*kq+0];
            a1 += hv.y*wr[4*kq+1];
            a2 += hv.z*wr[4*kq+2];
            a3 += hv.w*wr[4*kq+3];
          }
          float part = (a0+a1)+(a2+a3);
          float full = part + __shfl_xor(part, 1);
          if (!half){
            float pre = xcur + bsum + full;
            gates[g] = isG ? tanhf_(pre) : sigmoidf_(pre);
          }
        }
        __syncthreads();
        if (tid < 100){
          float cn = gates[100+tid]*c0[tid] + gates[tid]*gates[200+tid];
          c0[tid] = cn;
          float hn = gates[300+tid]*tanhf_(cn);
          h0[tid] = hn;
          hbuf[t*100+tid] = hn;
        }
        __syncthreads();
        xcur = xnext;
      }
    }
    // ------------- layer 1a: x-part pre-acts (no recurrence) -------------
    {
      float wx[52];
      float bsum = 0.f;
      if (act){
        #pragma unroll
        for (int j = 0; j < 52; ++j){
          int k = half*52 + j;
          wx[j] = (k < 100) ? w1xT[k*400 + g] : 0.f;
        }
        if (!half) bsum = bi1[g] + bh1[g];
        #pragma unroll 1
        for (int t = 0; t < 32; ++t){
          const float4* x4 = (const float4*)&hbuf[t*100];
          float a0=0.f,a1=0.f,a2=0.f,a3=0.f;
          #pragma unroll
          for (int kq = 0; kq < 13; ++kq){
            float4 xv = x4[kbase + kq];
            a0 += xv.x*wx[4*kq+0];
            a1 += xv.y*wx[4*kq+1];
            a2 += xv.z*wx[4*kq+2];
            a3 += xv.w*wx[4*kq+3];
          }
          float part = (a0+a1)+(a2+a3);
          float full = part + __shfl_xor(part, 1);
          if (!half) Xl1[t*400+g] = bsum + full;
        }
      }
      __syncthreads();
    }
    // ------------- layer 1b: recurrent -------------
    {
      float wh[52];
      if (act){
        #pragma unroll
        for (int j = 0; j < 52; ++j){
          int k = half*52 + j;
          wh[j] = (k < 100) ? w1hT[k*400 + g] : 0.f;
        }
      }
      #pragma unroll 1
      for (int t = 0; t < 32; ++t){
        if (act){
          const float4* h4 = (const float4*)h1;
          float a0=0.f,a1=0.f,a2=0.f,a3=0.f;
          #pragma unroll
          for (int kq = 0; kq < 13; ++kq){
            float4 hv = h4[kbase + kq];
            a0 += hv.x*wh[4*kq+0];
            a1 += hv.y*wh[4*kq+1];
            a2 += hv.z*wh[4*kq+2];
            a3 += hv.w*wh[4*kq+3];
          }
          float part = (a0+a1)+(a2+a3);
          float full = part + __shfl_xor(part, 1);
          if (!half){
            float pre = Xl1[t*400+g] + full;
            gates[g] = isG ? tanhf_(pre) : sigmoidf_(pre);
          }
        }
        __syncthreads();
        if (tid < 100){
          float cn = gates[100+tid]*c1[tid] + gates[tid]*gates[200+tid];
          c1[tid] = cn;
          float hn = gates[300+tid]*tanhf_(cn);
          h1[tid] = hn;
          if (t == 31){
            float* dst = s ? outR : outS;
            dst[b*100+tid] = hn;
          }
        }
        __syncthreads();
      }
    }
  }
}

// Final head: out = relu([outR|outS] @ fc1^T + b1) @ fc2^T + b2
__global__ __launch_bounds__(256) void head_k(
    const float* __restrict__ outR, const float* __restrict__ outS,
    const float* __restrict__ f1w, const float* __restrict__ f1b,
    const float* __restrict__ f2w, const float* __restrict__ f2b,
    float* __restrict__ out)
{
  __shared__ float xin[200];
  __shared__ float mid[512];
  int b = blockIdx.x, tid = threadIdx.x;
  if (tid < 100) xin[tid] = outR[b*100+tid];
  else if (tid < 200) xin[tid] = outS[b*100+tid-100];
  __syncthreads();
  for (int j = tid; j < 512; j += 256){
    float acc = f1b[j];
    #pragma unroll 4
    for (int k=0;k<200;k++) acc += xin[k]*f1w[j*200+k];
    mid[j] = fmaxf(acc, 0.f);
  }
  __syncthreads();
  if (tid < 130){
    float acc = f2b[tid];
    #pragma unroll 4
    for (int k=0;k<512;k++) acc += mid[k]*f2w[tid*512+k];
    out[b*130+tid] = acc;
  }
}

extern "C" void kernel_launch(void* const* d_in, const int* in_sizes, int n_in,
                              void* d_out, int out_size, void* d_ws, size_t ws_size,
                              hipStream_t stream)
{
  const float* obs  = (const float*)d_in[0];
  const float* data = (const float*)d_in[1];
  const float* c1w = (const float*)d_in[2];  const float* c1b = (const float*)d_in[3];
  const float* c2w = (const float*)d_in[4];  const float* c2b = (const float*)d_in[5];
  const float* c3w = (const float*)d_in[6];  const float* c3b = (const float*)d_in[7];
  const float* l1w = (const float*)d_in[8];  const float* l1b = (const float*)d_in[9];
  const float* l2w = (const float*)d_in[10]; const float* l2b = (const float*)d_in[11];
  const float* s_wih0=(const float*)d_in[12]; const float* s_whh0=(const float*)d_in[13];
  const float* s_bih0=(const float*)d_in[14]; const float* s_bhh0=(const float*)d_in[15];
  const float* s_wih1=(const float*)d_in[16]; const float* s_whh1=(const float*)d_in[17];
  const float* s_bih1=(const float*)d_in[18]; const float* s_bhh1=(const float*)d_in[19];
  const float* r_wih0=(const float*)d_in[20]; const float* r_whh0=(const float*)d_in[21];
  const float* r_bih0=(const float*)d_in[22]; const float* r_bhh0=(const float*)d_in[23];
  const float* r_wih1=(const float*)d_in[24]; const float* r_whh1=(const float*)d_in[25];
  const float* r_bih1=(const float*)d_in[26]; const float* r_bhh1=(const float*)d_in[27];
  const float* f1w=(const float*)d_in[28]; const float* f1b=(const float*)d_in[29];
  const float* f2w=(const float*)d_in[30]; const float* f2b=(const float*)d_in[31];
  float* out = (float*)d_out;
  (void)in_sizes; (void)n_in; (void)out_size;

  // ---- workspace layout (bytes, 256-aligned); total ≈ 67 MB ----
  char* p = (char*)d_ws;
  auto alloc = [&](size_t bytes){ void* r = (void*)p; p += (bytes + 255) & ~(size_t)255; return r; };
  unsigned short* data_bf = (unsigned short*)alloc((size_t)2048*1536*2);
  unsigned short* c1w_bf  = (unsigned short*)alloc((size_t)32*192*2);
  unsigned short* c2w_bf  = (unsigned short*)alloc((size_t)64*512*2);
  unsigned short* c3w_bf  = (unsigned short*)alloc((size_t)64*576*2);
  unsigned short* l1w_bf  = (unsigned short*)alloc((size_t)1024*1536*2);
  unsigned short* l2w_bf  = (unsigned short*)alloc((size_t)512*1024*2);
  unsigned short* wihS_bf = (unsigned short*)alloc((size_t)400*1536*2);
  unsigned short* wihR_bf = (unsigned short*)alloc((size_t)400*1536*2);
  unsigned short* conv1o  = (unsigned short*)alloc((size_t)2048*225*32*2);  // NHWC
  unsigned short* conv2o  = (unsigned short*)alloc((size_t)2048*36*64*2);   // NHWC
  unsigned short* feat    = (unsigned short*)alloc((size_t)2048*1536*2);
  unsigned short* lin1o   = (unsigned short*)alloc((size_t)2048*1024*2);
  float* X0s  = (float*)alloc((size_t)1024*400*4);
  float* X0r  = (float*)alloc((size_t)1024*400*4);
  float* wT   = (float*)alloc((size_t)6*40000*4);
  float* outS = (float*)alloc(3200*4);
  float* outR = (float*)alloc(3200*4);
  (void)ws_size;

  // ---- prep: casts / reorders (independent of GEMMs) ----
  cast_pad_k<<<1024,256,0,stream>>>(data, data_bf, 2048, 1500, 1536);
  cast_pad_k<<<512,256,0,stream>>>(l1w, l1w_bf, 1024, 1500, 1536);
  cast_pad_k<<<512,256,0,stream>>>(l2w, l2w_bf, 512, 1024, 1024);
  cast_pad_k<<<32,256,0,stream>>>(c1w, c1w_bf, 32, 192, 192);
  reorder_w_k<<<128,256,0,stream>>>(c2w, c2w_bf, 64, 32, 16);
  reorder_w_k<<<144,256,0,stream>>>(c3w, c3w_bf, 64, 64, 9);
  permute_wih_k<<<512,256,0,stream>>>(s_wih0, wihS_bf);
  permute_wih_k<<<512,256,0,stream>>>(r_wih0, wihR_bf);
  transpose6_k<<<dim3(157,6),256,0,stream>>>(s_whh0, s_wih1, s_whh1,
                                             r_whh0, r_wih1, r_whh1, wT);

  // ---- GEMM chain (bf16 MFMA, fp32 accumulate) ----
  // conv1: M=460800 N=32 K=192, obs fp32 NCHW gather -> NHWC bf16
  mgemm<128,32,4,1, 1,0,1,0, 3,64,64,8,8,4,15,15><<<dim3(3600,1),256,0,stream>>>(
      obs, c1w_bf, conv1o, c1b, 460800, 32, 192, 0, 32, 0);
  // conv2: M=73728 N=64 K=512, NHWC gather -> NHWC bf16
  mgemm<128,64,2,2, 2,0,1,0, 32,15,15,4,4,2,6,6><<<dim3(576,1),256,0,stream>>>(
      conv1o, c2w_bf, conv2o, c2b, 73728, 64, 512, 0, 64, 0);
  // lin1: M=2048 N=1024 K=1536(padded) -> bf16
  mgemm<128,64,2,2, 0,0,1,0, 1,1,1,1,1,1,1,1><<<dim3(16,16),256,0,stream>>>(
      data_bf, l1w_bf, lin1o, l1b, 2048, 1024, 1536, 1536, 1024, 0);
  // conv3: M=32768 N=64 K=576 -> feat cols [0,1024) in NHWC-flat order
  mgemm<128,64,2,2, 2,2,1,0, 64,6,6,3,3,1,4,4><<<dim3(256,1),256,0,stream>>>(
      conv2o, c3w_bf, feat, c3b, 32768, 64, 576, 0, 0, 1536);
  // lin2: M=2048 N=512 K=1024 -> feat cols [1024,1536)
  mgemm<128,64,2,2, 0,0,0,0, 1,1,1,1,1,1,1,1><<<dim3(16,8),256,0,stream>>>(
      lin1o, l2w_bf, feat + 1024, l2b, 2048, 512, 1024, 1024, 1536, 0);
  // LSTM layer-0 input pre-acts (fp32 out, no bias)
  mgemm<128,64,2,2, 0,3,0,1, 1,1,1,1,1,1,1,1><<<dim3(8,7),256,0,stream>>>(
      feat, wihS_bf, X0s, (const float*)nullptr, 1024, 400, 1536, 1536, 400, 0);
  mgemm<128,64,2,2, 0,3,0,1, 1,1,1,1,1,1,1,1><<<dim3(8,7),256,0,stream>>>(
      feat + (size_t)1024*1536, wihR_bf, X0r, (const float*)nullptr, 1024, 400, 1536, 1536, 400, 0);

  // ---- sequential LSTM (fp32) + head ----
  lstm_k<<<32,832,0,stream>>>(X0s, X0r, wT,
                              s_bih0,s_bhh0,s_bih1,s_bhh1,
                              r_bih0,r_bhh0,r_bih1,r_bhh1, outS, outR);
  head_k<<<32,256,0,stream>>>(outR, outS, f1w, f1b, f2w, f2b, out);
}

// Round 5
// 418.298 us; speedup vs baseline: 1.1687x; 1.0275x over previous
//
#include <hip/hip_runtime.h>
#include <math.h>

// ---------------------------------------------------------------------------
// NatureCNN: conv×3 (implicit-im2col bf16 MFMA GEMMs, NHWC intermediates)
// | lin1+relu -> lin2 (bf16 MFMA) -> concat feat -> wih0 pre-act GEMMs (fp32 out)
// -> 2×(2-layer LSTM, bf16-packed weights in regs, spill-free) -> head.
// ---------------------------------------------------------------------------

typedef __attribute__((ext_vector_type(4))) float f32x4;
typedef __attribute__((ext_vector_type(8))) short s16x8;
typedef __attribute__((ext_vector_type(8))) unsigned short u16x8;

__device__ __forceinline__ unsigned short f2bf(float f){
  union { float f; unsigned int u; } v; v.f = f;
  unsigned int r = (v.u + 0x7fffu + ((v.u >> 16) & 1u)) >> 16;
  return (unsigned short)r;
}
__device__ __forceinline__ float bflo(unsigned int u){
  union { unsigned int u; float f; } v; v.u = u << 16; return v.f;
}
__device__ __forceinline__ float bfhi(unsigned int u){
  union { unsigned int u; float f; } v; v.u = u & 0xffff0000u; return v.f;
}
__device__ __forceinline__ float sigmoidf_(float x){ return 1.0f/(1.0f+__expf(-x)); }
__device__ __forceinline__ float tanhf_(float x){
  float e = __expf(-2.0f*fabsf(x));
  float t = (1.0f - e)/(1.0f + e);
  return copysignf(t, x);
}

// ---------------------------------------------------------------------------
// prep kernels (tiny, memory-bound)
// ---------------------------------------------------------------------------
__global__ void cast_pad_k(const float* __restrict__ src, unsigned short* __restrict__ dst,
                           int rows, int ks, int kd){
  int total = rows*kd;
  for (int e = blockIdx.x*blockDim.x + threadIdx.x; e < total; e += gridDim.x*blockDim.x){
    int r = e / kd, k = e - r*kd;
    dst[e] = (k < ks) ? f2bf(src[(size_t)r*ks + k]) : (unsigned short)0;
  }
}
// OIHW -> O,(tap,ci) : dst[oc*K + tap*cin + ic] = src[oc*K + ic*khkw + tap]
__global__ void reorder_w_k(const float* __restrict__ src, unsigned short* __restrict__ dst,
                            int ocn, int cin, int khkw){
  int K = cin*khkw, total = ocn*K;
  for (int e = blockIdx.x*blockDim.x + threadIdx.x; e < total; e += gridDim.x*blockDim.x){
    int oc = e / K, r = e - oc*K;
    int tap = r / cin, ic = r - tap*cin;
    dst[e] = f2bf(src[(size_t)oc*K + ic*khkw + tap]);
  }
}
// wih0 [400][1536]: permute k<1024 from (oc*16+p) order to NHWC-flat (p*64+oc)
__global__ void permute_wih_k(const float* __restrict__ src, unsigned short* __restrict__ dst){
  int total = 400*1536;
  for (int e = blockIdx.x*blockDim.x + threadIdx.x; e < total; e += gridDim.x*blockDim.x){
    int g = e / 1536, k = e - g*1536;
    int ksrc = (k < 1024) ? ((k & 63)*16 + (k >> 6)) : k;
    dst[e] = f2bf(src[(size_t)g*1536 + ksrc]);
  }
}
// six [400][100] recurrent mats -> bf16-pair-packed [50][400] u32:
// dst[kk*400+g] = pack(bf16(src[g*100+2kk]), bf16(src[g*100+2kk+1]))
__global__ void transpose_pack6_k(const float* s0,const float* s1,const float* s2,
                                  const float* s3,const float* s4,const float* s5,
                                  unsigned int* __restrict__ dst){
  const float* srcs[6] = {s0,s1,s2,s3,s4,s5};
  const float* src = srcs[blockIdx.y];
  unsigned int* d = dst + (size_t)blockIdx.y*20000;
  int e = blockIdx.x*blockDim.x + threadIdx.x;
  if (e < 20000){
    int kk = e/400, g = e - kk*400;
    unsigned int lo = f2bf(src[g*100 + 2*kk]);
    unsigned int hi = f2bf(src[g*100 + 2*kk + 1]);
    d[e] = lo | (hi << 16);
  }
}

// ---------------------------------------------------------------------------
// bf16 MFMA GEMM: C = act(A * B^T + bias); B is [N][K] bf16 row-major.
// AMODE 0: A bf16 [M][lda].  1: conv1 gather from fp32 NCHW obs (k=ic*64+ky*8+kx).
//          2: NHWC bf16 conv gather (k=(ky*KW+kx)*CIN+ic).
// CMODE 0: bf16 row-major [M][ldc].  2: bf16 feat scatter (n*cstride + p*64 + col).
//          3: fp32 row-major (X0 path).
// All M are multiples of BM=128; K multiples of BK=64. NGUARD guards N (X0: N=400).
// ---------------------------------------------------------------------------
template<int BM,int BN,int WAVES_M,int WAVES_N,int AMODE,int CMODE,int RELU,int NGUARD,
         int CIN,int HI,int WI,int KH,int KW,int ST,int HO,int WO>
__global__ __launch_bounds__(256) void mgemm(
    const void* __restrict__ Av, const unsigned short* __restrict__ B,
    void* __restrict__ Cv, const float* __restrict__ bias,
    int M, int N, int K, int lda, int ldc, int cstride)
{
  constexpr int BK = 64;
  constexpr int WROWS = BM / WAVES_M;
  constexpr int WCOLS = BN / WAVES_N;
  constexpr int MF = WROWS / 16;
  constexpr int NF = WCOLS / 16;
  constexpr int HOWO = HO*WO;
  __shared__ unsigned short As[BM*BK];
  __shared__ unsigned short Bs[BN*BK];
  const int tid = threadIdx.x;
  const int bm = blockIdx.x * BM;
  const int bn = blockIdx.y * BN;
  const int lane = tid & 63, w = tid >> 6;
  const int wm = w / WAVES_N, wn = w % WAVES_N;
  const int m0 = wm * WROWS, n0 = wn * WCOLS;

  f32x4 acc[MF][NF] = {};

  const int ar = tid >> 1;           // A-stage row (BM=128 assumed)
  const int as0 = 4 * (tid & 1);     // A-stage slot base
  const int row_g = bm + ar;
  // im2col row decomposition (compile-time divisors)
  int a_n = 0, a_oy = 0, a_ox = 0;
  if (AMODE != 0){ a_n = row_g / HOWO; int p = row_g - a_n*HOWO; a_oy = p / WO; a_ox = p - a_oy*WO; }

  for (int kt = 0; kt < K; kt += BK){
    // ---- stage A ----
    #pragma unroll
    for (int si = 0; si < 4; ++si){
      int s = as0 + si;
      int k0 = kt + s*8;
      u16x8 val;
      if constexpr (AMODE == 0){
        val = *(const u16x8*)((const unsigned short*)Av + (size_t)row_g*lda + k0);
      } else if constexpr (AMODE == 1){
        int ic = k0 >> 6, r = k0 & 63, ky = r >> 3;   // kx0 == 0 (k0 % 8 == 0)
        const float* src = (const float*)Av +
            (((size_t)(a_n*CIN + ic)*HI + a_oy*ST + ky)*WI + a_ox*ST);
        f32x4 f0 = *(const f32x4*)src;
        f32x4 f1 = *(const f32x4*)(src + 4);
        val[0]=f2bf(f0[0]); val[1]=f2bf(f0[1]); val[2]=f2bf(f0[2]); val[3]=f2bf(f0[3]);
        val[4]=f2bf(f1[0]); val[5]=f2bf(f1[1]); val[6]=f2bf(f1[2]); val[7]=f2bf(f1[3]);
      } else {
        int tap = k0 / CIN, ic0 = k0 - tap*CIN;       // 8 | CIN, so 8-contig in ic
        int ky = tap / KW, kx = tap - ky*KW;
        const unsigned short* src = (const unsigned short*)Av +
            (((size_t)(a_n*HI + a_oy*ST + ky)*WI + a_ox*ST + kx)*CIN + ic0);
        val = *(const u16x8*)src;
      }
      int phys = s ^ ((ar >> 1) & 7);
      *(u16x8*)&As[ar*BK + phys*8] = val;
    }
    // ---- stage B ----
    if constexpr (BN == 64){
      int br = tid >> 2, bs0 = 2*(tid & 3);
      #pragma unroll
      for (int si = 0; si < 2; ++si){
        int s = bs0 + si, k0 = kt + s*8;
        int n_g = bn + br;
        u16x8 val = {};
        if (!NGUARD || n_g < N) val = *(const u16x8*)(B + (size_t)n_g*K + k0);
        int phys = s ^ ((br >> 1) & 7);
        *(u16x8*)&Bs[br*BK + phys*8] = val;
      }
    } else {  // BN == 32
      int br = tid >> 3, s = tid & 7, k0 = kt + s*8;
      int n_g = bn + br;
      u16x8 val = {};
      if (!NGUARD || n_g < N) val = *(const u16x8*)(B + (size_t)n_g*K + k0);
      int phys = s ^ ((br >> 1) & 7);
      *(u16x8*)&Bs[br*BK + phys*8] = val;
    }
    __syncthreads();
    // ---- compute: 2 MFMA k-steps per staged BK=64 ----
    #pragma unroll
    for (int ks = 0; ks < 2; ++ks){
      s16x8 a[MF], b[NF];
      #pragma unroll
      for (int i = 0; i < MF; ++i){
        int row = m0 + i*16 + (lane & 15);
        int phys = (ks*4 + (lane >> 4)) ^ ((row >> 1) & 7);
        a[i] = *(const s16x8*)&As[row*BK + phys*8];
      }
      #pragma unroll
      for (int j = 0; j < NF; ++j){
        int row = n0 + j*16 + (lane & 15);
        int phys = (ks*4 + (lane >> 4)) ^ ((row >> 1) & 7);
        b[j] = *(const s16x8*)&Bs[row*BK + phys*8];
      }
      #pragma unroll
      for (int i = 0; i < MF; ++i)
        #pragma unroll
        for (int j = 0; j < NF; ++j)
          acc[i][j] = __builtin_amdgcn_mfma_f32_16x16x32_bf16(a[i], b[j], acc[i][j], 0, 0, 0);
    }
    __syncthreads();
  }

  // ---- epilogue ----
  if constexpr (CMODE == 3){
    float* Cf = (float*)Cv;
    #pragma unroll
    for (int i = 0; i < MF; ++i)
      #pragma unroll
      for (int j = 0; j < NF; ++j){
        int col = bn + n0 + j*16 + (lane & 15);
        float bv = (bias && (!NGUARD || col < N)) ? bias[col] : 0.f;
        #pragma unroll
        for (int q = 0; q < 4; ++q){
          int row = bm + m0 + i*16 + (lane >> 4)*4 + q;
          float v = acc[i][j][q] + bv;
          if (RELU) v = fmaxf(v, 0.f);
          if (!NGUARD || col < N) Cf[(size_t)row*ldc + col] = v;
        }
      }
  } else {
    unsigned short* tile = As;   // reuse (BM*BN <= BM*BK)
    #pragma unroll
    for (int i = 0; i < MF; ++i)
      #pragma unroll
      for (int j = 0; j < NF; ++j){
        int col = n0 + j*16 + (lane & 15);
        float bv = bias ? bias[bn + col] : 0.f;
        #pragma unroll
        for (int q = 0; q < 4; ++q){
          int row = m0 + i*16 + (lane >> 4)*4 + q;
          float v = acc[i][j][q] + bv;
          if (RELU) v = fmaxf(v, 0.f);
          tile[row*BN + col] = f2bf(v);
        }
      }
    __syncthreads();
    unsigned short* Cu = (unsigned short*)Cv;
    constexpr int CHUNKS = (BM*BN)/(256*8);
    #pragma unroll
    for (int c = 0; c < CHUNKS; ++c){
      int flat = tid*8 + c*2048;
      int row = flat / BN, col = flat - (flat/BN)*BN;
      u16x8 v = *(const u16x8*)&tile[flat];
      int rg = bm + row;
      size_t addr;
      if constexpr (CMODE == 0) addr = (size_t)rg*ldc + bn + col;
      else { int n = rg >> 4, p = rg & 15; addr = (size_t)n*cstride + p*64 + col; }
      *(u16x8*)&Cu[addr] = v;
    }
  }
}

// ---------------------------------------------------------------------------
// LSTM: one block per segment; both stacks. 832 threads; thread pair
// (2g, 2g+1) owns gate g with a 50/50 k-split. Weights live as bf16 PAIRS
// packed in u32 registers (25 VGPRs/thread) -> spill-free even at a 64-VGPR
// budget. h stays fp32 (float2 LDS reads); unpack = 1 shift / 1 mask.
// Gate threads apply sigmoid/tanh (400-way parallel); tid<100 combiner does
// only the c/h elementwise update.
// ---------------------------------------------------------------------------
__global__ __launch_bounds__(832,4) void lstm_k(
    const float* __restrict__ X0s, const float* __restrict__ X0r,
    const unsigned int* __restrict__ wpk,  // 6 x [50][400] u32 packed bf16 pairs
    const float* __restrict__ s_bih0, const float* __restrict__ s_bhh0,
    const float* __restrict__ s_bih1, const float* __restrict__ s_bhh1,
    const float* __restrict__ r_bih0, const float* __restrict__ r_bhh0,
    const float* __restrict__ r_bih1, const float* __restrict__ r_bhh1,
    float* __restrict__ outS, float* __restrict__ outR)
{
  __shared__ alignas(16) float h0[104];
  __shared__ alignas(16) float c0[104];
  __shared__ alignas(16) float h1[104];
  __shared__ alignas(16) float c1[104];
  __shared__ float gates[400];                 // ACTIVATED gate values
  __shared__ alignas(16) float hbuf[3208];     // 32 x 100 (+pad)
  __shared__ alignas(16) float Xl1[12800];     // layer-1 x-part pre-acts, 32 x 400

  const int b = blockIdx.x, tid = threadIdx.x;
  const int g = tid >> 1, half = tid & 1;
  const bool act = (tid < 800);                // g < 400
  const int kb = half * 25;                    // packed-pair base (k = 2*kb)
  const bool isG = (g >= 200) & (g < 300);     // tanh gate vs sigmoid gates

  if (tid < 104){ h0[tid]=0.f; c0[tid]=0.f; h1[tid]=0.f; c1[tid]=0.f; }
  if (tid >= 824) hbuf[3200 + (tid-824)] = 0.f;   // pad tail (8 entries)
  __syncthreads();

  #pragma unroll 1
  for (int s = 0; s < 2; ++s){
    const float* Xp = (s ? X0r : X0s) + (size_t)b*32*400;
    const unsigned int* w0P  = wpk + (size_t)(s ? 3 : 0)*20000;
    const unsigned int* w1xP = wpk + (size_t)(s ? 4 : 1)*20000;
    const unsigned int* w1hP = wpk + (size_t)(s ? 5 : 2)*20000;
    const float* bi0 = s ? r_bih0 : s_bih0;
    const float* bh0 = s ? r_bhh0 : s_bhh0;
    const float* bi1 = s ? r_bih1 : s_bih1;
    const float* bh1 = s ? r_bhh1 : s_bhh1;

    // ------------- layer 0 (recurrent) -------------
    {
      unsigned int wrp[25];
      float bsum = 0.f, xcur = 0.f;
      if (act){
        #pragma unroll
        for (int j = 0; j < 25; ++j) wrp[j] = w0P[(kb + j)*400 + g];
        if (!half){ bsum = bi0[g] + bh0[g]; xcur = Xp[g]; }
      }
      #pragma unroll 1
      for (int t = 0; t < 32; ++t){
        float xnext = 0.f;
        if (act && !half && t < 31) xnext = Xp[(t+1)*400 + g];
        if (act){
          const float2* h2 = (const float2*)h0;
          float a0=0.f,a1=0.f;
          #pragma unroll
          for (int j = 0; j < 25; ++j){
            unsigned int u = wrp[j];
            float2 hv = h2[kb + j];
            a0 += hv.x * bflo(u);
            a1 += hv.y * bfhi(u);
          }
          float part = a0 + a1;
          float full = part + __shfl_xor(part, 1);
          if (!half){
            float pre = xcur + bsum + full;
            gates[g] = isG ? tanhf_(pre) : sigmoidf_(pre);
          }
        }
        __syncthreads();
        if (tid < 100){
          float cn = gates[100+tid]*c0[tid] + gates[tid]*gates[200+tid];
          c0[tid] = cn;
          float hn = gates[300+tid]*tanhf_(cn);
          h0[tid] = hn;
          hbuf[t*100+tid] = hn;
        }
        __syncthreads();
        xcur = xnext;
      }
    }
    // ------------- layer 1a: x-part pre-acts (no recurrence) -------------
    {
      unsigned int wxp[25];
      float bsum = 0.f;
      if (act){
        #pragma unroll
        for (int j = 0; j < 25; ++j) wxp[j] = w1xP[(kb + j)*400 + g];
        if (!half) bsum = bi1[g] + bh1[g];
        #pragma unroll 1
        for (int t = 0; t < 32; ++t){
          const float2* x2 = (const float2*)&hbuf[t*100];
          float a0=0.f,a1=0.f;
          #pragma unroll
          for (int j = 0; j < 25; ++j){
            unsigned int u = wxp[j];
            float2 xv = x2[kb + j];
            a0 += xv.x * bflo(u);
            a1 += xv.y * bfhi(u);
          }
          float part = a0 + a1;
          float full = part + __shfl_xor(part, 1);
          if (!half) Xl1[t*400+g] = bsum + full;
        }
      }
      __syncthreads();
    }
    // ------------- layer 1b: recurrent -------------
    {
      unsigned int whp[25];
      if (act){
        #pragma unroll
        for (int j = 0; j < 25; ++j) whp[j] = w1hP[(kb + j)*400 + g];
      }
      #pragma unroll 1
      for (int t = 0; t < 32; ++t){
        if (act){
          const float2* h2 = (const float2*)h1;
          float a0=0.f,a1=0.f;
          #pragma unroll
          for (int j = 0; j < 25; ++j){
            unsigned int u = whp[j];
            float2 hv = h2[kb + j];
            a0 += hv.x * bflo(u);
            a1 += hv.y * bfhi(u);
          }
          float part = a0 + a1;
          float full = part + __shfl_xor(part, 1);
          if (!half){
            float pre = Xl1[t*400+g] + full;
            gates[g] = isG ? tanhf_(pre) : sigmoidf_(pre);
          }
        }
        __syncthreads();
        if (tid < 100){
          float cn = gates[100+tid]*c1[tid] + gates[tid]*gates[200+tid];
          c1[tid] = cn;
          float hn = gates[300+tid]*tanhf_(cn);
          h1[tid] = hn;
          if (t == 31){
            float* dst = s ? outR : outS;
            dst[b*100+tid] = hn;
          }
        }
        __syncthreads();
      }
    }
  }
}

// Final head: out = relu([outR|outS] @ fc1^T + b1) @ fc2^T + b2
__global__ __launch_bounds__(256) void head_k(
    const float* __restrict__ outR, const float* __restrict__ outS,
    const float* __restrict__ f1w, const float* __restrict__ f1b,
    const float* __restrict__ f2w, const float* __restrict__ f2b,
    float* __restrict__ out)
{
  __shared__ float xin[200];
  __shared__ float mid[512];
  int b = blockIdx.x, tid = threadIdx.x;
  if (tid < 100) xin[tid] = outR[b*100+tid];
  else if (tid < 200) xin[tid] = outS[b*100+tid-100];
  __syncthreads();
  for (int j = tid; j < 512; j += 256){
    float acc = f1b[j];
    #pragma unroll 4
    for (int k=0;k<200;k++) acc += xin[k]*f1w[j*200+k];
    mid[j] = fmaxf(acc, 0.f);
  }
  __syncthreads();
  if (tid < 130){
    float acc = f2b[tid];
    #pragma unroll 4
    for (int k=0;k<512;k++) acc += mid[k]*f2w[tid*512+k];
    out[b*130+tid] = acc;
  }
}

extern "C" void kernel_launch(void* const* d_in, const int* in_sizes, int n_in,
                              void* d_out, int out_size, void* d_ws, size_t ws_size,
                              hipStream_t stream)
{
  const float* obs  = (const float*)d_in[0];
  const float* data = (const float*)d_in[1];
  const float* c1w = (const float*)d_in[2];  const float* c1b = (const float*)d_in[3];
  const float* c2w = (const float*)d_in[4];  const float* c2b = (const float*)d_in[5];
  const float* c3w = (const float*)d_in[6];  const float* c3b = (const float*)d_in[7];
  const float* l1w = (const float*)d_in[8];  const float* l1b = (const float*)d_in[9];
  const float* l2w = (const float*)d_in[10]; const float* l2b = (const float*)d_in[11];
  const float* s_wih0=(const float*)d_in[12]; const float* s_whh0=(const float*)d_in[13];
  const float* s_bih0=(const float*)d_in[14]; const float* s_bhh0=(const float*)d_in[15];
  const float* s_wih1=(const float*)d_in[16]; const float* s_whh1=(const float*)d_in[17];
  const float* s_bih1=(const float*)d_in[18]; const float* s_bhh1=(const float*)d_in[19];
  const float* r_wih0=(const float*)d_in[20]; const float* r_whh0=(const float*)d_in[21];
  const float* r_bih0=(const float*)d_in[22]; const float* r_bhh0=(const float*)d_in[23];
  const float* r_wih1=(const float*)d_in[24]; const float* r_whh1=(const float*)d_in[25];
  const float* r_bih1=(const float*)d_in[26]; const float* r_bhh1=(const float*)d_in[27];
  const float* f1w=(const float*)d_in[28]; const float* f1b=(const float*)d_in[29];
  const float* f2w=(const float*)d_in[30]; const float* f2b=(const float*)d_in[31];
  float* out = (float*)d_out;
  (void)in_sizes; (void)n_in; (void)out_size;

  // ---- workspace layout (bytes, 256-aligned); total ≈ 67 MB ----
  char* p = (char*)d_ws;
  auto alloc = [&](size_t bytes){ void* r = (void*)p; p += (bytes + 255) & ~(size_t)255; return r; };
  unsigned short* data_bf = (unsigned short*)alloc((size_t)2048*1536*2);
  unsigned short* c1w_bf  = (unsigned short*)alloc((size_t)32*192*2);
  unsigned short* c2w_bf  = (unsigned short*)alloc((size_t)64*512*2);
  unsigned short* c3w_bf  = (unsigned short*)alloc((size_t)64*576*2);
  unsigned short* l1w_bf  = (unsigned short*)alloc((size_t)1024*1536*2);
  unsigned short* l2w_bf  = (unsigned short*)alloc((size_t)512*1024*2);
  unsigned short* wihS_bf = (unsigned short*)alloc((size_t)400*1536*2);
  unsigned short* wihR_bf = (unsigned short*)alloc((size_t)400*1536*2);
  unsigned short* conv1o  = (unsigned short*)alloc((size_t)2048*225*32*2);  // NHWC
  unsigned short* conv2o  = (unsigned short*)alloc((size_t)2048*36*64*2);   // NHWC
  unsigned short* feat    = (unsigned short*)alloc((size_t)2048*1536*2);
  unsigned short* lin1o   = (unsigned short*)alloc((size_t)2048*1024*2);
  float* X0s  = (float*)alloc((size_t)1024*400*4);
  float* X0r  = (float*)alloc((size_t)1024*400*4);
  unsigned int* wpk = (unsigned int*)alloc((size_t)6*20000*4);
  float* outS = (float*)alloc(3200*4);
  float* outR = (float*)alloc(3200*4);
  (void)ws_size;

  // ---- prep: casts / reorders (independent of GEMMs) ----
  cast_pad_k<<<1024,256,0,stream>>>(data, data_bf, 2048, 1500, 1536);
  cast_pad_k<<<512,256,0,stream>>>(l1w, l1w_bf, 1024, 1500, 1536);
  cast_pad_k<<<512,256,0,stream>>>(l2w, l2w_bf, 512, 1024, 1024);
  cast_pad_k<<<32,256,0,stream>>>(c1w, c1w_bf, 32, 192, 192);
  reorder_w_k<<<128,256,0,stream>>>(c2w, c2w_bf, 64, 32, 16);
  reorder_w_k<<<144,256,0,stream>>>(c3w, c3w_bf, 64, 64, 9);
  permute_wih_k<<<512,256,0,stream>>>(s_wih0, wihS_bf);
  permute_wih_k<<<512,256,0,stream>>>(r_wih0, wihR_bf);
  transpose_pack6_k<<<dim3(79,6),256,0,stream>>>(s_whh0, s_wih1, s_whh1,
                                                 r_whh0, r_wih1, r_whh1, wpk);

  // ---- GEMM chain (bf16 MFMA, fp32 accumulate) ----
  // conv1: M=460800 N=32 K=192, obs fp32 NCHW gather -> NHWC bf16
  mgemm<128,32,4,1, 1,0,1,0, 3,64,64,8,8,4,15,15><<<dim3(3600,1),256,0,stream>>>(
      obs, c1w_bf, conv1o, c1b, 460800, 32, 192, 0, 32, 0);
  // conv2: M=73728 N=64 K=512, NHWC gather -> NHWC bf16
  mgemm<128,64,2,2, 2,0,1,0, 32,15,15,4,4,2,6,6><<<dim3(576,1),256,0,stream>>>(
      conv1o, c2w_bf, conv2o, c2b, 73728, 64, 512, 0, 64, 0);
  // lin1: M=2048 N=1024 K=1536(padded) -> bf16
  mgemm<128,64,2,2, 0,0,1,0, 1,1,1,1,1,1,1,1><<<dim3(16,16),256,0,stream>>>(
      data_bf, l1w_bf, lin1o, l1b, 2048, 1024, 1536, 1536, 1024, 0);
  // conv3: M=32768 N=64 K=576 -> feat cols [0,1024) in NHWC-flat order
  mgemm<128,64,2,2, 2,2,1,0, 64,6,6,3,3,1,4,4><<<dim3(256,1),256,0,stream>>>(
      conv2o, c3w_bf, feat, c3b, 32768, 64, 576, 0, 0, 1536);
  // lin2: M=2048 N=512 K=1024 -> feat cols [1024,1536)
  mgemm<128,64,2,2, 0,0,0,0, 1,1,1,1,1,1,1,1><<<dim3(16,8),256,0,stream>>>(
      lin1o, l2w_bf, feat + 1024, l2b, 2048, 512, 1024, 1024, 1536, 0);
  // LSTM layer-0 input pre-acts (fp32 out, no bias)
  mgemm<128,64,2,2, 0,3,0,1, 1,1,1,1,1,1,1,1><<<dim3(8,7),256,0,stream>>>(
      feat, wihS_bf, X0s, (const float*)nullptr, 1024, 400, 1536, 1536, 400, 0);
  mgemm<128,64,2,2, 0,3,0,1, 1,1,1,1,1,1,1,1><<<dim3(8,7),256,0,stream>>>(
      feat + (size_t)1024*1536, wihR_bf, X0r, (const float*)nullptr, 1024, 400, 1536, 1536, 400, 0);

  // ---- sequential LSTM + head ----
  lstm_k<<<32,832,0,stream>>>(X0s, X0r, wpk,
                              s_bih0,s_bhh0,s_bih1,s_bhh1,
                              r_bih0,r_bhh0,r_bih1,r_bhh1, outS, outR);
  head_k<<<32,256,0,stream>>>(outR, outS, f1w, f1b, f2w, f2b, out);
}